// Round 1
// baseline (1667.950 us; speedup 1.0000x reference)
//
#include <hip/hip_runtime.h>

// VQ-VAE vector quantizer step on MI355X (gfx950).
// Round 3: correctness hardening.
//   - zq_oh_k: all 16B stores to misaligned bases now via __builtin_memcpy
//     (gfx950 supports unaligned global_store_dwordx4; removes the UB that
//     corrupted the idx region post-timing).
//   - idx output moved into scatter_k (reads idxw anyway) to isolate it from
//     the vector-store stream.
// argmin_k unchanged (855us; MFMA split-bf16 path is the next perf lever).

#define NT 131072   // tokens
#define NE 1024     // codebook entries
#define ED 256      // embedding dim

// Output layout (flat f32, reference return order)
static const size_t OFF_QL   = 0;            // quant_loss (1)
static const size_t OFF_CL   = 1;            // commit_loss (1)
static const size_t OFF_ZQ   = 2;            // z_q_st (131072*256)
static const size_t OFF_PPL  = 33554434ULL;  // perplexity (1)
static const size_t OFF_OH   = 33554435ULL;  // min_encodings (131072*1024)
static const size_t OFF_IDX  = 167772163ULL; // idx (131072)
static const size_t OFF_NEMB = 167903235ULL; // new_emb_weight (1024*256)
static const size_t OFF_NN   = 168165379ULL; // new_n_mat (1024)
static const size_t OFF_NM   = 168166403ULL; // new_m_mat (1024*256)

// ---------------------------------------------------------------- row norms
__global__ __launch_bounds__(256) void rownorm_k(const float* __restrict__ x,
                                                 float* __restrict__ o, int nrows) {
  int wid  = blockIdx.x * 4 + (threadIdx.x >> 6);  // one wave per row
  int lane = threadIdx.x & 63;
  if (wid >= nrows) return;
  float4 v = ((const float4*)(x + (size_t)wid * ED))[lane];
  float s = v.x * v.x + v.y * v.y + v.z * v.z + v.w * v.w;
  #pragma unroll
  for (int off = 32; off; off >>= 1) s += __shfl_down(s, off, 64);
  if (lane == 0) o[wid] = s;
}

// ------------------------------------------------- distance GEMM + argmin
// (unchanged)
__global__ __launch_bounds__(256) void argmin_k(
    const float* __restrict__ z, const float* __restrict__ emb,
    const float* __restrict__ znorm, const float* __restrict__ enorm,
    int* __restrict__ idxw) {
  __shared__ float zs[16][68];
  __shared__ float es[16][260];
  __shared__ float rv[64][32];
  __shared__ int   ri[64][32];

  const int tid  = threadIdx.x;
  const int tr   = tid >> 5, tc = tid & 31;
  const int row0 = blockIdx.x * 64;
  const int zr   = tid >> 2, zk0 = (tid & 3) * 4;

  float zn[8];
  #pragma unroll
  for (int i = 0; i < 8; i++) zn[i] = znorm[row0 + tr * 8 + i];

  float minv[8]; int mini[8];
  #pragma unroll
  for (int i = 0; i < 8; i++) { minv[i] = 3.4028235e38f; mini[i] = 0; }

  for (int ct = 0; ct < 4; ++ct) {
    const int c0 = ct * 256;
    float en[8];
    #pragma unroll
    for (int j = 0; j < 8; j++) en[j] = enorm[c0 + tc * 8 + j];

    float acc[8][8];
    #pragma unroll
    for (int i = 0; i < 8; i++)
      #pragma unroll
      for (int j = 0; j < 8; j++) acc[i][j] = 0.f;

    for (int kt = 0; kt < 16; ++kt) {
      const int k0 = kt * 16;
      float4 zv = *(const float4*)(z + (size_t)(row0 + zr) * ED + k0 + zk0);
      const float* er = emb + (size_t)(c0 + tid) * ED + k0;
      float4 e0 = ((const float4*)er)[0];
      float4 e1 = ((const float4*)er)[1];
      float4 e2 = ((const float4*)er)[2];
      float4 e3 = ((const float4*)er)[3];
      __syncthreads();
      zs[zk0 + 0][zr] = zv.x; zs[zk0 + 1][zr] = zv.y;
      zs[zk0 + 2][zr] = zv.z; zs[zk0 + 3][zr] = zv.w;
      es[0][tid] = e0.x;  es[1][tid] = e0.y;  es[2][tid] = e0.z;  es[3][tid] = e0.w;
      es[4][tid] = e1.x;  es[5][tid] = e1.y;  es[6][tid] = e1.z;  es[7][tid] = e1.w;
      es[8][tid] = e2.x;  es[9][tid] = e2.y;  es[10][tid] = e2.z; es[11][tid] = e2.w;
      es[12][tid] = e3.x; es[13][tid] = e3.y; es[14][tid] = e3.z; es[15][tid] = e3.w;
      __syncthreads();
      #pragma unroll
      for (int k = 0; k < 16; k++) {
        float a[8], b[8];
        *(float4*)&a[0] = *(const float4*)&zs[k][tr * 8];
        *(float4*)&a[4] = *(const float4*)&zs[k][tr * 8 + 4];
        *(float4*)&b[0] = *(const float4*)&es[k][tc * 8];
        *(float4*)&b[4] = *(const float4*)&es[k][tc * 8 + 4];
        #pragma unroll
        for (int i = 0; i < 8; i++)
          #pragma unroll
          for (int j = 0; j < 8; j++) acc[i][j] += a[i] * b[j];
      }
    }
    #pragma unroll
    for (int i = 0; i < 8; i++) {
      #pragma unroll
      for (int j = 0; j < 8; j++) {
        float s = zn[i] + en[j];
        float d = s - 2.0f * acc[i][j];
        int   c = c0 + tc * 8 + j;
        if (d < minv[i]) { minv[i] = d; mini[i] = c; }
      }
    }
  }

  __syncthreads();
  #pragma unroll
  for (int i = 0; i < 8; i++) { rv[tr * 8 + i][tc] = minv[i]; ri[tr * 8 + i][tc] = mini[i]; }
  __syncthreads();
  if (tid < 64) {
    float bv = rv[tid][0]; int bi = ri[tid][0];
    for (int t = 1; t < 32; t++) {
      float v = rv[tid][t]; int ii = ri[tid][t];
      if (v < bv || (v == bv && ii < bi)) { bv = v; bi = ii; }
    }
    idxw[row0 + tid] = bi;
  }
}

// ------------------------- streaming per-token outputs: z_q, one-hot, loss
// All 16B stores to potentially misaligned bases (OFF_ZQ = 2 floats -> 8B
// aligned; OFF_OH odd -> 4B aligned) go through __builtin_memcpy: clang emits
// align-4 global_store_dwordx4 (legal on gfx950), no alignment UB.
__global__ __launch_bounds__(256) void zq_oh_k(
    const float* __restrict__ z, const float* __restrict__ emb,
    const int* __restrict__ idxw, float* __restrict__ out,
    double* __restrict__ lossacc) {
  const int t = threadIdx.x;
  const int tl = t >> 6, lane = t & 63;
  const int tok = blockIdx.x * 4 + tl;
  const int id = idxw[tok];

  float4 z4 = ((const float4*)(z   + (size_t)tok * ED))[lane];
  float4 e4 = ((const float4*)(emb + (size_t)id  * ED))[lane];
  float4 q;
  q.x = z4.x + (e4.x - z4.x);   // straight-through, exact ref formula
  q.y = z4.y + (e4.y - z4.y);
  q.z = z4.z + (e4.z - z4.z);
  q.w = z4.w + (e4.w - z4.w);
  __builtin_memcpy(out + OFF_ZQ + (size_t)tok * ED + (size_t)lane * 4, &q, 16);

  float dx = e4.x - z4.x, dy = e4.y - z4.y, dz = e4.z - z4.z, dw = e4.w - z4.w;
  double lsum = (double)(dx * dx) + (double)(dy * dy)
              + (double)(dz * dz) + (double)(dw * dw);

  // one-hot row (streaming 16B writes, value computed in-register)
  float* ohb = out + OFF_OH + (size_t)tok * NE;
  #pragma unroll
  for (int it = 0; it < 4; ++it) {
    int f4i = it * 64 + lane;
    int c0 = f4i * 4;
    float v[4];
    v[0] = (c0 + 0 == id) ? 1.0f : 0.0f;
    v[1] = (c0 + 1 == id) ? 1.0f : 0.0f;
    v[2] = (c0 + 2 == id) ? 1.0f : 0.0f;
    v[3] = (c0 + 3 == id) ? 1.0f : 0.0f;
    __builtin_memcpy(ohb + (size_t)f4i * 4, v, 16);
  }

  #pragma unroll
  for (int off = 32; off; off >>= 1) lsum += __shfl_down(lsum, off, 64);
  __shared__ double lred[4];
  if (lane == 0) lred[tl] = lsum;
  __syncthreads();
  if (t == 0)
    unsafeAtomicAdd(&lossacc[blockIdx.x & 255],
                    lred[0] + lred[1] + lred[2] + lred[3]);
}

// ------------------------------------------------ histogram (LDS-privatized)
__global__ __launch_bounds__(256) void hist_k(const int* __restrict__ idxw,
                                              int* __restrict__ counts) {
  __shared__ int lc[NE];
  for (int i = threadIdx.x; i < NE; i += 256) lc[i] = 0;
  __syncthreads();
  const int stride = gridDim.x * 256;
  for (int i = blockIdx.x * 256 + threadIdx.x; i < NT; i += stride)
    atomicAdd(&lc[idxw[i]], 1);
  __syncthreads();
  for (int i = threadIdx.x; i < NE; i += 256) {
    int v = lc[i];
    if (v) atomicAdd(&counts[i], v);
  }
}

// -------------------------------------------------------- exclusive prefix sum
__global__ void scan_k(const int* __restrict__ counts, int* __restrict__ offsets) {
  if (threadIdx.x == 0) {
    int s = 0;
    for (int i = 0; i < NE; i++) { offsets[i] = s; s += counts[i]; }
  }
}

// -------------------------------------------------- scatter tokens into buckets
// Also writes the idx output (float) — isolated from zq_oh_k's vector stores.
__global__ __launch_bounds__(256) void scatter_k(
    const int* __restrict__ idxw, const int* __restrict__ offsets,
    int* __restrict__ cursor, int* __restrict__ bucket,
    float* __restrict__ out) {
  int i = blockIdx.x * 256 + threadIdx.x;
  int id = idxw[i];
  out[OFF_IDX + i] = (float)id;
  int pos = atomicAdd(&cursor[id], 1);
  bucket[offsets[id] + pos] = i;
}

// ------------------- per-code segment sum (no atomics) fused with EMA update
__global__ __launch_bounds__(256) void segsum_k(
    const float* __restrict__ z, const float* __restrict__ nmat,
    const float* __restrict__ mmat, const int* __restrict__ counts,
    const int* __restrict__ offsets, const int* __restrict__ bucket,
    float* __restrict__ out) {
  const int j = blockIdx.x, t = threadIdx.x;
  const int cnt = counts[j], off = offsets[j];
  float s = 0.f;
  int i = 0;
  for (; i + 4 <= cnt; i += 4) {   // unroll x4: overlap the 4 row gathers
    int t0 = bucket[off + i + 0], t1 = bucket[off + i + 1];
    int t2 = bucket[off + i + 2], t3 = bucket[off + i + 3];
    float a = z[(size_t)t0 * ED + t];
    float b = z[(size_t)t1 * ED + t];
    float c = z[(size_t)t2 * ED + t];
    float d = z[(size_t)t3 * ED + t];
    s += a; s += b; s += c; s += d;
  }
  for (; i < cnt; ++i) s += z[(size_t)bucket[off + i] * ED + t];

  float newn = nmat[j] * 0.99f + (float)cnt * 0.01f;
  if (t == 0) out[OFF_NN + j] = newn;
  const size_t o = (size_t)j * ED + t;
  float newm = 0.99f * mmat[o] + 0.01f * s;
  out[OFF_NM + o]   = newm;
  out[OFF_NEMB + o] = newm / newn;
}

// ------------------------------------------------------- scalar finalizers
__global__ __launch_bounds__(256) void scalars_k(
    const double* __restrict__ lossacc, const int* __restrict__ counts,
    float* __restrict__ out) {
  const int t = threadIdx.x;
  double lsum = lossacc[t];
  double h = 0.0;
  for (int c = t; c < NE; c += 256) {
    double e = (double)counts[c] / (double)NT;
    h += e * log(e + 1e-10);
  }
  #pragma unroll
  for (int off = 32; off; off >>= 1) {
    lsum += __shfl_down(lsum, off, 64);
    h    += __shfl_down(h,    off, 64);
  }
  __shared__ double sl[4], sh[4];
  if ((t & 63) == 0) { sl[t >> 6] = lsum; sh[t >> 6] = h; }
  __syncthreads();
  if (t == 0) {
    double mean = (sl[0] + sl[1] + sl[2] + sl[3]) / (double)((size_t)NT * ED);
    out[OFF_QL]  = (float)mean;
    out[OFF_CL]  = (float)(0.25 * mean);
    out[OFF_PPL] = (float)exp(-(sh[0] + sh[1] + sh[2] + sh[3]));
  }
}

// ------------------------------------------------------------------ launch
extern "C" void kernel_launch(void* const* d_in, const int* in_sizes, int n_in,
                              void* d_out, int out_size, void* d_ws, size_t ws_size,
                              hipStream_t stream) {
  const float* z    = (const float*)d_in[0];
  const float* emb  = (const float*)d_in[1];
  const float* nmat = (const float*)d_in[2];
  const float* mmat = (const float*)d_in[3];
  float* out = (float*)d_out;
  char*  ws  = (char*)d_ws;

  // ws layout (byte offsets):
  //   0       lossacc  double[256]  (2 KB, pad to 4 KB)
  //   4096    counts   int[1024]
  //   8192    cursor   int[1024]
  //   12288   offsets  int[1024]
  //   16384   bucket   int[131072]  (512 KB)
  //   540672  idxw     int[131072]  (512 KB)
  //   1064960 znorm    float[131072] (512 KB)
  //   1589248 enorm    float[1024]  (4 KB)
  double* lossacc = (double*)ws;
  int*    counts  = (int*)(ws + 4096);
  int*    cursor  = (int*)(ws + 8192);
  int*    offsets = (int*)(ws + 12288);
  int*    bucket  = (int*)(ws + 16384);
  int*    idxw    = (int*)(ws + 540672);
  float*  znorm   = (float*)(ws + 1064960);
  float*  enorm   = (float*)(ws + 1589248);

  hipMemsetAsync(ws, 0, 12288, stream);  // lossacc + counts + cursor

  hipLaunchKernelGGL(rownorm_k, dim3(NT / 4), dim3(256), 0, stream, z, znorm, NT);
  hipLaunchKernelGGL(rownorm_k, dim3(NE / 4), dim3(256), 0, stream, emb, enorm, NE);
  hipLaunchKernelGGL(argmin_k, dim3(NT / 64), dim3(256), 0, stream,
                     z, emb, znorm, enorm, idxw);
  hipLaunchKernelGGL(zq_oh_k, dim3(NT / 4), dim3(256), 0, stream,
                     z, emb, idxw, out, lossacc);
  hipLaunchKernelGGL(hist_k, dim3(64), dim3(256), 0, stream, idxw, counts);
  hipLaunchKernelGGL(scan_k, dim3(1), dim3(64), 0, stream, counts, offsets);
  hipLaunchKernelGGL(scatter_k, dim3(NT / 256), dim3(256), 0, stream,
                     idxw, offsets, cursor, bucket, out);
  hipLaunchKernelGGL(segsum_k, dim3(NE), dim3(256), 0, stream,
                     z, nmat, mmat, counts, offsets, bucket, out);
  hipLaunchKernelGGL(scalars_k, dim3(1), dim3(256), 0, stream,
                     lossacc, counts, out);
}

// Round 3
// 1311.048 us; speedup vs baseline: 1.2722x; 1.2722x over previous
//
#include <hip/hip_runtime.h>

// VQ-VAE vector quantizer step on MI355X (gfx950).
// Round 5: coarse MFMA argmin + exact fp32 refine for near-ties.
//   - eprep_k: codebook -> f16 (e*1024), XOR-swizzled tile layout
//   - argmin_coarse_k: 1 MFMA/frag f16 distance, min1/min2 tracking;
//     unambiguous winners (gap >= 4e-4) finalized; near-ties flagged.
//   - argmin_refine_k: flagged tokens get a full 1024-code fp32 scan with
//     round-1's exact arithmetic (proven bit-match vs numpy ref).
// Margin derivation: coarse dd error worst ~1e-4 (f16 rounding of z,e),
// ref fp32 quantization window ~1.3e-4 at d~256; margin 4e-4 covers both.
// All other kernels byte-identical to the round-3 passing version.

#define NT 131072   // tokens
#define NE 1024     // codebook entries
#define ED 256      // embedding dim

typedef _Float16 f16;
typedef f16  f16x8 __attribute__((ext_vector_type(8)));
typedef float f32x4 __attribute__((ext_vector_type(4)));

// Output layout (flat f32, reference return order)
static const size_t OFF_QL   = 0;            // quant_loss (1)
static const size_t OFF_CL   = 1;            // commit_loss (1)
static const size_t OFF_ZQ   = 2;            // z_q_st (131072*256)
static const size_t OFF_PPL  = 33554434ULL;  // perplexity (1)
static const size_t OFF_OH   = 33554435ULL;  // min_encodings (131072*1024)
static const size_t OFF_IDX  = 167772163ULL; // idx (131072)
static const size_t OFF_NEMB = 167903235ULL; // new_emb_weight (1024*256)
static const size_t OFF_NN   = 168165379ULL; // new_n_mat (1024)
static const size_t OFF_NM   = 168166403ULL; // new_m_mat (1024*256)

// ---------------------------------------------------------------- row norms
__global__ __launch_bounds__(256) void rownorm_k(const float* __restrict__ x,
                                                 float* __restrict__ o, int nrows) {
  int wid  = blockIdx.x * 4 + (threadIdx.x >> 6);  // one wave per row
  int lane = threadIdx.x & 63;
  if (wid >= nrows) return;
  float4 v = ((const float4*)(x + (size_t)wid * ED))[lane];
  float s = v.x * v.x + v.y * v.y + v.z * v.z + v.w * v.w;
  #pragma unroll
  for (int off = 32; off; off >>= 1) s += __shfl_down(s, off, 64);
  if (lane == 0) o[wid] = s;
}

// ------------------------------------- codebook prep: f16 (e*1024) swizzled
// Tile t (32 codes) = contiguous 16 KB block; 16B unit
// g = (c_local<<5) | (kq ^ (c_local&7)) holds e[c][8*kq .. 8*kq+8).
// Linear LDS copy then gives conflict-light ds_read_b128 B-fragments.
__global__ __launch_bounds__(256) void eprep_k(const float* __restrict__ emb,
                                               char* __restrict__ eswz) {
  const int t  = threadIdx.x;
  const int c  = blockIdx.x * 8 + (t >> 5);   // code
  const int kq = t & 31;                      // 8-elem unit within row
  const float* er = emb + (size_t)c * ED + kq * 8;
  float4 v0 = ((const float4*)er)[0];
  float4 v1 = ((const float4*)er)[1];
  float vv[8] = {v0.x, v0.y, v0.z, v0.w, v1.x, v1.y, v1.z, v1.w};
  f16x8 h;
  #pragma unroll
  for (int i = 0; i < 8; ++i) h[i] = (f16)(vv[i] * 1024.0f);  // exact pow2 scale
  const int tile = c >> 5, cl = c & 31;
  const int g = (cl << 5) | (kq ^ (cl & 7));
  *(f16x8*)(eswz + (size_t)tile * 16384 + (size_t)g * 16) = h;
}

// --------------------------------------------- coarse MFMA distance argmin
// dd_j = ||e_j||^2 - 2 z.e_j  (the token-invariant ||z||^2 dropped: argmin
// unchanged, and dd values ~0.05 keep full fp32 resolution).
// acc = sum zh*(e*1024)h via mfma_f32_16x16x32_f16 -> dd = en - acc/512.
// Winner finalized iff min2-min1 >= MARGIN, else token flagged for refine.
__global__ __launch_bounds__(256) void argmin_coarse_k(
    const float* __restrict__ z, const char* __restrict__ eswz,
    const float* __restrict__ enorm, int* __restrict__ idxw,
    int* __restrict__ nflag, int* __restrict__ flaglist) {
  __shared__ uint4 etile[1024];                   // 16 KB
  const char* eb = (const char*)etile;

  const int tid  = threadIdx.x;
  const int w    = tid >> 6, lane = tid & 63;
  const int lr   = lane & 15, kg = lane >> 4;
  const int r0   = blockIdx.x * 128 + w * 32;

  // A fragments: row = lane&15, k = kt*32 + kg*8 + i  (validated round 2/4)
  f16x8 ah[2][8];
  #pragma unroll
  for (int mf = 0; mf < 2; ++mf) {
    const float* zr = z + (size_t)(r0 + mf * 16 + lr) * ED + kg * 8;
    #pragma unroll
    for (int kt = 0; kt < 8; ++kt) {
      float4 a = ((const float4*)(zr + kt * 32))[0];
      float4 b = ((const float4*)(zr + kt * 32))[1];
      float vv[8] = {a.x, a.y, a.z, a.w, b.x, b.y, b.z, b.w};
      #pragma unroll
      for (int i = 0; i < 8; ++i) ah[mf][kt][i] = (f16)vv[i];
    }
  }

  float m1[2][4], m2[2][4]; int i1[2][4];
  #pragma unroll
  for (int mf = 0; mf < 2; ++mf)
    #pragma unroll
    for (int r = 0; r < 4; ++r) {
      m1[mf][r] = 3.4028235e38f; m2[mf][r] = 3.4028235e38f; i1[mf][r] = 0;
    }

  const uint4* gsrc = (const uint4*)eswz;
  for (int ct = 0; ct < 32; ++ct) {
    __syncthreads();
    const uint4* src = gsrc + (size_t)ct * 1024;
    etile[tid]       = src[tid];
    etile[tid + 256] = src[tid + 256];
    etile[tid + 512] = src[tid + 512];
    etile[tid + 768] = src[tid + 768];
    __syncthreads();

    f32x4 acc[2][2];
    #pragma unroll
    for (int mf = 0; mf < 2; ++mf)
      #pragma unroll
      for (int nf = 0; nf < 2; ++nf) acc[mf][nf] = (f32x4){0.f, 0.f, 0.f, 0.f};

    #pragma unroll
    for (int kt = 0; kt < 8; ++kt) {
      f16x8 bh[2];
      #pragma unroll
      for (int nf = 0; nf < 2; ++nf) {
        const int cl = nf * 16 + lr;
        const int kq = kt * 4 + kg;
        const int u  = (cl << 5) | (kq ^ (cl & 7));
        bh[nf] = *(const f16x8*)(eb + u * 16);
      }
      #pragma unroll
      for (int nf = 0; nf < 2; ++nf)
        #pragma unroll
        for (int mf = 0; mf < 2; ++mf)
          acc[mf][nf] = __builtin_amdgcn_mfma_f32_16x16x32_f16(
              ah[mf][kt], bh[nf], acc[mf][nf], 0, 0, 0);
    }

    // C/D: col = lane&15, row = kg*4 + r
    #pragma unroll
    for (int nf = 0; nf < 2; ++nf) {
      const int c = ct * 32 + nf * 16 + lr;
      const float en = enorm[c];
      #pragma unroll
      for (int mf = 0; mf < 2; ++mf)
        #pragma unroll
        for (int r = 0; r < 4; ++r) {
          float dd = en - 0.001953125f * acc[mf][nf][r];   // en - 2*dot
          if (dd < m1[mf][r]) {
            m2[mf][r] = m1[mf][r]; m1[mf][r] = dd; i1[mf][r] = c;
          } else if (dd < m2[mf][r]) {
            m2[mf][r] = dd;
          }
        }
    }
  }

  // reduce (min1,min2) across the 16 column-lanes (lane bits 0..3)
  #pragma unroll
  for (int mf = 0; mf < 2; ++mf)
    #pragma unroll
    for (int r = 0; r < 4; ++r) {
      float a1 = m1[mf][r]; int ai = i1[mf][r]; float a2 = m2[mf][r];
      #pragma unroll
      for (int off = 1; off < 16; off <<= 1) {
        float o1 = __shfl_xor(a1, off, 64);
        int   oi = __shfl_xor(ai, off, 64);
        float o2 = __shfl_xor(a2, off, 64);
        if (o1 < a1) { a2 = fminf(a1, o2); a1 = o1; ai = oi; }
        else         { a2 = fminf(a2, o1); }
      }
      if (lr == 0) {
        const int row = r0 + mf * 16 + kg * 4 + r;
        idxw[row] = ai;                          // provisional if flagged
        if (a2 - a1 < 4.0e-4f) {
          int p = atomicAdd(nflag, 1);
          flaglist[p] = row;
        }
      }
    }
}

// ------------------------- exact fp32 refine (round-1 arithmetic) for flags
// 16 flagged tokens per block; each thread owns 4 consecutive codes and
// accumulates a single fp32 fma chain over k ascending (matches round-1's
// proven-bit-exact form). First-index tie-break preserved end to end.
__global__ __launch_bounds__(256) void argmin_refine_k(
    const float* __restrict__ z, const float* __restrict__ emb,
    const float* __restrict__ znorm, const float* __restrict__ enorm,
    const int* __restrict__ nflag, const int* __restrict__ flaglist,
    int* __restrict__ idxw) {
  const int nf = *nflag;
  const int b0 = blockIdx.x * 16;
  if (b0 >= nf) return;

  __shared__ float zl[16][256];    // 16 KB staged z rows
  __shared__ int   toks[16];
  __shared__ float rv[4][16];
  __shared__ int   ri[4][16];

  const int t = threadIdx.x;
  if (t < 16) {
    int li = b0 + t;
    toks[t] = flaglist[li < nf ? li : b0];   // tail clamps to a valid token
  }
  __syncthreads();

  #pragma unroll
  for (int i = 0; i < 4; ++i) {
    int li = t + i * 256;                    // 0..1023 float4 units
    int row = li >> 6, c4 = li & 63;
    float4 v = ((const float4*)(z + (size_t)toks[row] * ED))[c4];
    *(float4*)&zl[row][c4 * 4] = v;
  }
  __syncthreads();

  float acc[4][16];
  #pragma unroll
  for (int cc = 0; cc < 4; ++cc)
    #pragma unroll
    for (int tk = 0; tk < 16; ++tk) acc[cc][tk] = 0.f;

  for (int c4 = 0; c4 < 64; ++c4) {
    float4 e[4];
    #pragma unroll
    for (int cc = 0; cc < 4; ++cc)
      e[cc] = ((const float4*)(emb + (size_t)(t * 4 + cc) * ED))[c4];
    #pragma unroll
    for (int tk = 0; tk < 16; ++tk) {
      float4 zv = *(const float4*)&zl[tk][c4 * 4];
      #pragma unroll
      for (int cc = 0; cc < 4; ++cc) {
        acc[cc][tk] += zv.x * e[cc].x;
        acc[cc][tk] += zv.y * e[cc].y;
        acc[cc][tk] += zv.z * e[cc].z;
        acc[cc][tk] += zv.w * e[cc].w;
      }
    }
  }

  float en[4];
  #pragma unroll
  for (int cc = 0; cc < 4; ++cc) en[cc] = enorm[t * 4 + cc];

  const int wv = t >> 6, lane = t & 63;
  for (int tk = 0; tk < 16; ++tk) {
    const float zn = znorm[toks[tk]];
    float bv = 3.4028235e38f; int bi = 0;
    #pragma unroll
    for (int cc = 0; cc < 4; ++cc) {
      float s = zn + en[cc];                  // exact round-1 expression
      float d = s - 2.0f * acc[cc][tk];
      int   c = t * 4 + cc;
      if (d < bv) { bv = d; bi = c; }
    }
    #pragma unroll
    for (int off = 32; off; off >>= 1) {
      float ov = __shfl_down(bv, off, 64);
      int   oi = __shfl_down(bi, off, 64);
      if (ov < bv || (ov == bv && oi < bi)) { bv = ov; bi = oi; }
    }
    if (lane == 0) { rv[wv][tk] = bv; ri[wv][tk] = bi; }
  }
  __syncthreads();
  if (t < 16) {
    float bv = rv[0][t]; int bi = ri[0][t];
    #pragma unroll
    for (int wq = 1; wq < 4; ++wq) {
      float ov = rv[wq][t]; int oi = ri[wq][t];
      if (ov < bv || (ov == bv && oi < bi)) { bv = ov; bi = oi; }
    }
    idxw[toks[t]] = bi;
  }
}

// ------------------------- streaming per-token outputs: z_q, one-hot, loss
__global__ __launch_bounds__(256) void zq_oh_k(
    const float* __restrict__ z, const float* __restrict__ emb,
    const int* __restrict__ idxw, float* __restrict__ out,
    double* __restrict__ lossacc) {
  const int t = threadIdx.x;
  const int tl = t >> 6, lane = t & 63;
  const int tok = blockIdx.x * 4 + tl;
  const int id = idxw[tok];

  float4 z4 = ((const float4*)(z   + (size_t)tok * ED))[lane];
  float4 e4 = ((const float4*)(emb + (size_t)id  * ED))[lane];
  float4 q;
  q.x = z4.x + (e4.x - z4.x);   // straight-through, exact ref formula
  q.y = z4.y + (e4.y - z4.y);
  q.z = z4.z + (e4.z - z4.z);
  q.w = z4.w + (e4.w - z4.w);
  __builtin_memcpy(out + OFF_ZQ + (size_t)tok * ED + (size_t)lane * 4, &q, 16);

  float dx = e4.x - z4.x, dy = e4.y - z4.y, dz = e4.z - z4.z, dw = e4.w - z4.w;
  double lsum = (double)(dx * dx) + (double)(dy * dy)
              + (double)(dz * dz) + (double)(dw * dw);

  float* ohb = out + OFF_OH + (size_t)tok * NE;
  #pragma unroll
  for (int it = 0; it < 4; ++it) {
    int f4i = it * 64 + lane;
    int c0 = f4i * 4;
    float v[4];
    v[0] = (c0 + 0 == id) ? 1.0f : 0.0f;
    v[1] = (c0 + 1 == id) ? 1.0f : 0.0f;
    v[2] = (c0 + 2 == id) ? 1.0f : 0.0f;
    v[3] = (c0 + 3 == id) ? 1.0f : 0.0f;
    __builtin_memcpy(ohb + (size_t)f4i * 4, v, 16);
  }

  #pragma unroll
  for (int off = 32; off; off >>= 1) lsum += __shfl_down(lsum, off, 64);
  __shared__ double lred[4];
  if (lane == 0) lred[tl] = lsum;
  __syncthreads();
  if (t == 0)
    unsafeAtomicAdd(&lossacc[blockIdx.x & 255],
                    lred[0] + lred[1] + lred[2] + lred[3]);
}

// ------------------------------------------------ histogram (LDS-privatized)
__global__ __launch_bounds__(256) void hist_k(const int* __restrict__ idxw,
                                              int* __restrict__ counts) {
  __shared__ int lc[NE];
  for (int i = threadIdx.x; i < NE; i += 256) lc[i] = 0;
  __syncthreads();
  const int stride = gridDim.x * 256;
  for (int i = blockIdx.x * 256 + threadIdx.x; i < NT; i += stride)
    atomicAdd(&lc[idxw[i]], 1);
  __syncthreads();
  for (int i = threadIdx.x; i < NE; i += 256) {
    int v = lc[i];
    if (v) atomicAdd(&counts[i], v);
  }
}

// -------------------------------------------------------- exclusive prefix sum
__global__ void scan_k(const int* __restrict__ counts, int* __restrict__ offsets) {
  if (threadIdx.x == 0) {
    int s = 0;
    for (int i = 0; i < NE; i++) { offsets[i] = s; s += counts[i]; }
  }
}

// -------------------------------------------------- scatter tokens into buckets
__global__ __launch_bounds__(256) void scatter_k(
    const int* __restrict__ idxw, const int* __restrict__ offsets,
    int* __restrict__ cursor, int* __restrict__ bucket,
    float* __restrict__ out) {
  int i = blockIdx.x * 256 + threadIdx.x;
  int id = idxw[i];
  out[OFF_IDX + i] = (float)id;
  int pos = atomicAdd(&cursor[id], 1);
  bucket[offsets[id] + pos] = i;
}

// ------------------- per-code segment sum (no atomics) fused with EMA update
__global__ __launch_bounds__(256) void segsum_k(
    const float* __restrict__ z, const float* __restrict__ nmat,
    const float* __restrict__ mmat, const int* __restrict__ counts,
    const int* __restrict__ offsets, const int* __restrict__ bucket,
    float* __restrict__ out) {
  const int j = blockIdx.x, t = threadIdx.x;
  const int cnt = counts[j], off = offsets[j];
  float s = 0.f;
  int i = 0;
  for (; i + 4 <= cnt; i += 4) {
    int t0 = bucket[off + i + 0], t1 = bucket[off + i + 1];
    int t2 = bucket[off + i + 2], t3 = bucket[off + i + 3];
    float a = z[(size_t)t0 * ED + t];
    float b = z[(size_t)t1 * ED + t];
    float c = z[(size_t)t2 * ED + t];
    float d = z[(size_t)t3 * ED + t];
    s += a; s += b; s += c; s += d;
  }
  for (; i < cnt; ++i) s += z[(size_t)bucket[off + i] * ED + t];

  float newn = nmat[j] * 0.99f + (float)cnt * 0.01f;
  if (t == 0) out[OFF_NN + j] = newn;
  const size_t o = (size_t)j * ED + t;
  float newm = 0.99f * mmat[o] + 0.01f * s;
  out[OFF_NM + o]   = newm;
  out[OFF_NEMB + o] = newm / newn;
}

// ------------------------------------------------------- scalar finalizers
__global__ __launch_bounds__(256) void scalars_k(
    const double* __restrict__ lossacc, const int* __restrict__ counts,
    float* __restrict__ out) {
  const int t = threadIdx.x;
  double lsum = lossacc[t];
  double h = 0.0;
  for (int c = t; c < NE; c += 256) {
    double e = (double)counts[c] / (double)NT;
    h += e * log(e + 1e-10);
  }
  #pragma unroll
  for (int off = 32; off; off >>= 1) {
    lsum += __shfl_down(lsum, off, 64);
    h    += __shfl_down(h,    off, 64);
  }
  __shared__ double sl[4], sh[4];
  if ((t & 63) == 0) { sl[t >> 6] = lsum; sh[t >> 6] = h; }
  __syncthreads();
  if (t == 0) {
    double mean = (sl[0] + sl[1] + sl[2] + sl[3]) / (double)((size_t)NT * ED);
    out[OFF_QL]  = (float)mean;
    out[OFF_CL]  = (float)(0.25 * mean);
    out[OFF_PPL] = (float)exp(-(sh[0] + sh[1] + sh[2] + sh[3]));
  }
}

// ------------------------------------------------------------------ launch
extern "C" void kernel_launch(void* const* d_in, const int* in_sizes, int n_in,
                              void* d_out, int out_size, void* d_ws, size_t ws_size,
                              hipStream_t stream) {
  const float* z    = (const float*)d_in[0];
  const float* emb  = (const float*)d_in[1];
  const float* nmat = (const float*)d_in[2];
  const float* mmat = (const float*)d_in[3];
  float* out = (float*)d_out;
  char*  ws  = (char*)d_ws;

  // ws layout (byte offsets):
  //   0       lossacc  double[256]  (2 KB)
  //   2048    nflag    int (zeroed by memset)
  //   4096    counts   int[1024]
  //   8192    cursor   int[1024]
  //   12288   offsets  int[1024]
  //   16384   bucket   int[131072]  (512 KB)
  //   540672  idxw     int[131072]  (512 KB)
  //   1064960 znorm    float[131072] (512 KB)
  //   1589248 enorm    float[1024]  (4 KB)
  //   1593344 eswz     f16 swizzled tiles (512 KB)
  //   2117632 flaglist int[131072]  (512 KB)
  double* lossacc = (double*)ws;
  int*    nflag   = (int*)(ws + 2048);
  int*    counts  = (int*)(ws + 4096);
  int*    cursor  = (int*)(ws + 8192);
  int*    offsets = (int*)(ws + 12288);
  int*    bucket  = (int*)(ws + 16384);
  int*    idxw    = (int*)(ws + 540672);
  float*  znorm   = (float*)(ws + 1064960);
  float*  enorm   = (float*)(ws + 1589248);
  char*   eswz    = ws + 1593344;
  int*    flaglist= (int*)(ws + 2117632);

  hipMemsetAsync(ws, 0, 12288, stream);  // lossacc + nflag + counts + cursor

  hipLaunchKernelGGL(rownorm_k, dim3(NT / 4), dim3(256), 0, stream, z, znorm, NT);
  hipLaunchKernelGGL(rownorm_k, dim3(NE / 4), dim3(256), 0, stream, emb, enorm, NE);
  hipLaunchKernelGGL(eprep_k, dim3(NE / 8), dim3(256), 0, stream, emb, eswz);
  hipLaunchKernelGGL(argmin_coarse_k, dim3(NT / 128), dim3(256), 0, stream,
                     z, eswz, enorm, idxw, nflag, flaglist);
  hipLaunchKernelGGL(argmin_refine_k, dim3(NT / 16), dim3(256), 0, stream,
                     z, emb, znorm, enorm, nflag, flaglist, idxw);
  hipLaunchKernelGGL(zq_oh_k, dim3(NT / 4), dim3(256), 0, stream,
                     z, emb, idxw, out, lossacc);
  hipLaunchKernelGGL(hist_k, dim3(64), dim3(256), 0, stream, idxw, counts);
  hipLaunchKernelGGL(scan_k, dim3(1), dim3(64), 0, stream, counts, offsets);
  hipLaunchKernelGGL(scatter_k, dim3(NT / 256), dim3(256), 0, stream,
                     idxw, offsets, cursor, bucket, out);
  hipLaunchKernelGGL(segsum_k, dim3(NE), dim3(256), 0, stream,
                     z, nmat, mmat, counts, offsets, bucket, out);
  hipLaunchKernelGGL(scalars_k, dim3(1), dim3(256), 0, stream,
                     lossacc, counts, out);
}